// Round 4
// baseline (226.563 us; speedup 1.0000x reference)
//
#include <hip/hip_runtime.h>
#include <hip/hip_fp16.h>
#include <math.h>

#define LRELU_ALPHA 0.2f
#define NEG_INF -1000000000.0f
#define L2E 1.44269504088896340736f  // log2(e)

constexpr int B_ = 8, N_ = 2048, FIN = 128, FOUT = 64;

typedef _Float16 __attribute__((ext_vector_type(8))) f16x8;
typedef float __attribute__((ext_vector_type(4))) f32x4;

// async global->LDS, 16B per lane; lane l's data lands at ldsbase + l*16
__device__ __forceinline__ void gload16(const void* g, void* l) {
  __builtin_amdgcn_global_load_lds(
      (const __attribute__((address_space(1))) void*)g,
      (__attribute__((address_space(3))) void*)l, 16, 0, 0);
}

// ---------------------------------------------------------------------------
// Kernel 1 (unchanged, proven): Wh = h @ W^T (fp32), emitted as fp16
// transposed WhT[b][o][n]; also s1 = Wh@a1, s2 = Wh@a2 (fp32).
// ---------------------------------------------------------------------------
__global__ __launch_bounds__(256) void k_wh(
    const float* __restrict__ h, const float* __restrict__ W,
    const float* __restrict__ a, unsigned short* __restrict__ WhT,
    float* __restrict__ s1, float* __restrict__ s2) {
  __shared__ float Wt[128][65];  // [f][o]: read bank (f+o)%32 -> conflict-free
  __shared__ float hs[16][128];

  const int t = threadIdx.x;
  const int row0 = blockIdx.x * 16;

  for (int e = t; e < 64 * 128; e += 256) {
    int o = e >> 7, f = e & 127;
    Wt[f][o] = W[e];
  }
  {
    const float4* hg = (const float4*)(h + (size_t)row0 * FIN);
    for (int i4 = t; i4 < 16 * 32; i4 += 256) {
      int r = i4 >> 5, f4 = i4 & 31;
      *(float4*)&hs[r][f4 * 4] = hg[i4];
    }
  }
  __syncthreads();

  const int wave = t >> 6, lane = t & 63;  // lane = o
  float acc[4] = {0.f, 0.f, 0.f, 0.f};
#pragma unroll 4
  for (int f4 = 0; f4 < 32; ++f4) {
    float w0 = Wt[4 * f4 + 0][lane], w1 = Wt[4 * f4 + 1][lane];
    float w2 = Wt[4 * f4 + 2][lane], w3 = Wt[4 * f4 + 3][lane];
#pragma unroll
    for (int r = 0; r < 4; ++r) {
      float4 hv = *(const float4*)&hs[wave * 4 + r][f4 * 4];
      acc[r] += hv.x * w0 + hv.y * w1 + hv.z * w2 + hv.w * w3;
    }
  }

  const float a1v = a[lane], a2v = a[64 + lane];
  const int b = row0 / N_;
#pragma unroll
  for (int r = 0; r < 4; ++r) {
    const int row = row0 + wave * 4 + r;
    const int n = row - b * N_;
    const float v = acc[r];
    WhT[((size_t)b * 64 + lane) * N_ + n] = __half_as_ushort(__float2half(v));
    float p1 = v * a1v, p2 = v * a2v;
#pragma unroll
    for (int d = 32; d; d >>= 1) {
      p1 += __shfl_xor(p1, d, 64);
      p2 += __shfl_xor(p2, d, 64);
    }
    if (lane == 0) { s1[row] = p1; s2[row] = p2; }
  }
}

// ---------------------------------------------------------------------------
// Kernel 2 v4: adj direct-to-register (3 named slots, issued 3 chunks ahead,
// pinned between asm vmcnt fences so the compiler cannot collapse the
// pipeline); WhT via DMA-LDS (4 bufs x 8 KB, 2 DMA per wave per chunk —
// balanced across all 4 waves); s2 in LDS (staged once, broadcast reads).
// Per-wave vm-ops per iter = 4 adj loads + 2 DMA = 6 -> steady wait
// vmcnt(12) keeps chunks c+1,c+2 fully in flight across every barrier.
// Tail: last STAGE/ISSUE is chunk 31 (c=28); peel 29/30/31 @ vmcnt 12/6/0.
// vs v3b: ds_read_b128 per chunk per wave 12 -> 8; DMA instrs 16 -> 8;
// adj LDS round-trip (8 KB write + 8 KB read per chunk) eliminated.
// ---------------------------------------------------------------------------
__global__ __launch_bounds__(256, 2) void k_attn(
    const unsigned short* __restrict__ WhT,
    const float* __restrict__ s1g, const float* __restrict__ s2g,
    const int* __restrict__ adj, float* __restrict__ out) {
  __shared__ __align__(16) unsigned char sbuf[4][8 * 1024];
  __shared__ float s2s[N_];

  const int t = threadIdx.x;
  const int wave = t >> 6, lane = t & 63;
  const int m = lane & 15, q = lane >> 4;
  const int b = blockIdx.y;
  const int i0 = blockIdx.x * 32;
  const int rg = wave & 1;         // row-group (rows rg*16..+16)
  const int p0 = (wave >> 1) * 2;  // first o-group of this wave's pair

  const unsigned short* whB = WhT + (size_t)b * 64 * N_;
  const int* adjR = adj + (size_t)b * N_ * N_ + (size_t)(i0 + rg * 16 + m) * N_;

  // preload s2 row-block (8 KB), pre-scaled by log2(e)
  {
    const float4* s2R = (const float4*)(s2g + (size_t)b * N_);
    for (int i = t; i < N_ / 4; i += 256) {
      float4 v = s2R[i];
      v.x *= L2E; v.y *= L2E; v.z *= L2E; v.w *= L2E;
      ((float4*)s2s)[i] = v;
    }
  }

  const float s1r = s1g[b * N_ + i0 + rg * 16 + m];
  const float c1 = (s1r - 2.0f) * L2E;                // x-2 branch (base-2)
  const float c2 = (LRELU_ALPHA * s1r - 2.0f) * L2E;  // 0.2x-2 branch

  f16x8 ones;
#pragma unroll
  for (int j = 0; j < 8; ++j) ones[j] = (_Float16)1.0f;

  // WhT DMA: wave stages o-group g = wave, slots (g*2+ks)*1024 + lane*16.
  // Per-lane src (bytes): (wave*16+m)*2N + c*128 + ks*64 + q*16.
  const unsigned char* whP0 =
      (const unsigned char*)(whB + (size_t)(wave * 16 + m) * N_ + q * 8);
  const unsigned char* whP1 = whP0 + 64;  // ks=1

#define STAGE(c)                                                            \
  {                                                                         \
    gload16(whP0 + (size_t)(c) * 128, &sbuf[(c) & 3][(wave * 2 + 0) * 1024]); \
    gload16(whP1 + (size_t)(c) * 128, &sbuf[(c) & 3][(wave * 2 + 1) * 1024]); \
  }
  // adj: per-lane 32B per ks (8 ints), 2 ks slices -> 4 int4 per chunk
#define ISSUE_ADJ(S, c)                 \
  {                                     \
    const int* ap = adjR + (c) * 64 + q * 8; \
    S##0 = *(const int4*)(ap);          \
    S##1 = *(const int4*)(ap + 4);      \
    S##2 = *(const int4*)(ap + 32);     \
    S##3 = *(const int4*)(ap + 36);     \
  }
#define CONSUME(S, c)                                                        \
  {                                                                          \
    const unsigned char* Bb = &sbuf[(c) & 3][0];                             \
    _Pragma("unroll") for (int ks = 0; ks < 2; ++ks) {                       \
      int4 A0 = ks ? S##2 : S##0;                                            \
      int4 A1 = ks ? S##3 : S##1;                                            \
      const float* sp = &s2s[(c) * 64 + ks * 32 + q * 8];                    \
      float4 sv0 = *(const float4*)sp;                                       \
      float4 sv1 = *(const float4*)(sp + 4);                                 \
      float xs[8] = {sv0.x, sv0.y, sv0.z, sv0.w, sv1.x, sv1.y, sv1.z, sv1.w};\
      int avs[8] = {A0.x, A0.y, A0.z, A0.w, A1.x, A1.y, A1.z, A1.w};         \
      f16x8 af;                                                              \
      _Pragma("unroll") for (int j = 0; j < 8; ++j) {                        \
        float x = xs[j];                                                     \
        float e = fmaxf(c1 + x, fmaf(LRELU_ALPHA, x, c2));                   \
        e = avs[j] ? e : NEG_INF;                                            \
        af[j] = (_Float16)__builtin_amdgcn_exp2f(e);  /* masked -> 0 */      \
      }                                                                      \
      f16x8 b0 = *(const f16x8*)(Bb + ((p0 + 0) * 2 + ks) * 1024 + lane * 16);\
      f16x8 b1 = *(const f16x8*)(Bb + ((p0 + 1) * 2 + ks) * 1024 + lane * 16);\
      acc0 = __builtin_amdgcn_mfma_f32_16x16x32_f16(af, b0, acc0, 0, 0, 0);  \
      acc1 = __builtin_amdgcn_mfma_f32_16x16x32_f16(af, b1, acc1, 0, 0, 0);  \
      accS = __builtin_amdgcn_mfma_f32_16x16x32_f16(af, ones, accS, 0, 0, 0);\
    }                                                                        \
  }
#define ITERX(c, S, VMS)                        \
  {                                             \
    asm volatile("s_waitcnt " VMS ::: "memory");\
    __builtin_amdgcn_s_barrier();               \
    CONSUME(S, c)                               \
  }

  int4 rA0, rA1, rA2, rA3, rB0, rB1, rB2, rB3, rC0, rC1, rC2, rC3;
  f32x4 acc0 = {0.f, 0.f, 0.f, 0.f}, acc1 = acc0, accS = acc0;

  // prologue: chunks 0..2 in flight (regs + DMA); full drain once
  // (also publishes s2s).
  ISSUE_ADJ(rA, 0) STAGE(0)
  ISSUE_ADJ(rB, 1) STAGE(1)
  ISSUE_ADJ(rC, 2) STAGE(2)
  __syncthreads();

  for (int cb = 0; cb < 27; cb += 3) {
    ITERX(cb + 0, rA, "vmcnt(12)") ISSUE_ADJ(rA, cb + 3) STAGE(cb + 3)
    ITERX(cb + 1, rB, "vmcnt(12)") ISSUE_ADJ(rB, cb + 4) STAGE(cb + 4)
    ITERX(cb + 2, rC, "vmcnt(12)") ISSUE_ADJ(rC, cb + 5) STAGE(cb + 5)
  }
  ITERX(27, rA, "vmcnt(12)") ISSUE_ADJ(rA, 30) STAGE(30)
  ITERX(28, rB, "vmcnt(12)") ISSUE_ADJ(rB, 31) STAGE(31)  // last: chunk 31
  ITERX(29, rC, "vmcnt(12)")
  ITERX(30, rA, "vmcnt(6)")
  ITERX(31, rB, "vmcnt(0)")

  // C/D layout: row_in_tile = q*4 + r, col = m; accS[r] = rowsum(q*4+r)
#pragma unroll
  for (int r = 0; r < 4; ++r) {
    const int ri = q * 4 + r;
    const float l = accS[r];
    const float inv = (l == 0.f) ? 1.f : 1.f / l;  // fully-masked row guard
    const size_t row = (size_t)b * N_ + i0 + rg * 16 + ri;
    out[row * FOUT + (p0 + 0) * 16 + m] = acc0[r] * inv;
    out[row * FOUT + (p0 + 1) * 16 + m] = acc1[r] * inv;
  }
#undef STAGE
#undef ISSUE_ADJ
#undef CONSUME
#undef ITERX
}

extern "C" void kernel_launch(void* const* d_in, const int* in_sizes, int n_in,
                              void* d_out, int out_size, void* d_ws, size_t ws_size,
                              hipStream_t stream) {
  const float* h   = (const float*)d_in[0];
  const int*   adj = (const int*)d_in[1];
  const float* W   = (const float*)d_in[2];
  const float* a   = (const float*)d_in[3];
  float* out = (float*)d_out;

  // ws: WhT fp16 (2 MB) | s1 (64 KB) | s2 (64 KB)
  unsigned short* WhT = (unsigned short*)d_ws;
  float* s1 = (float*)(WhT + (size_t)B_ * 64 * N_);
  float* s2 = s1 + (size_t)B_ * N_;

  k_wh<<<dim3(B_ * N_ / 16), 256, 0, stream>>>(h, W, a, WhT, s1, s2);
  k_attn<<<dim3(N_ / 32, B_), 256, 0, stream>>>(WhT, s1, s2, adj, out);
}